// Round 1
// baseline (135.714 us; speedup 1.0000x reference)
//
#include <hip/hip_runtime.h>

// Reprojection multi-rig model.
// out[i] = intrs[cam]*(p_cam.xy/p_cam.z) + pps[cam] - points_2d[i]
// where p_cam = R(q)*points_3d[pi] + t,
//       q = rel_q (x) ref_q,  t = rel_t + R(rel_q)*ref_t
// Quaternions stored [x,y,z,w]; rotation p + 2*(w*(v x p) + v x (v x p)).
//
// R1: latency-bound on scattered gathers (VALUBusy 12.8%, HBM 31%).
//  - repack pre-kernel: ref_poses -> 2xfloat4/group, points_3d -> float4/pt
//    (gathers 10 dword instrs/elem -> 3 dwordx4 instrs/elem, all 16B-aligned)
//  - 2 elems/thread with float4/int4 streaming loads (2x MLP/wave)
//  - nontemporal on streams so they don't evict gather tables from L2

typedef float f4 __attribute__((ext_vector_type(4)));
typedef float f2 __attribute__((ext_vector_type(2)));
typedef int   i4 __attribute__((ext_vector_type(4)));
typedef int   i2 __attribute__((ext_vector_type(2)));

enum { NPTS = 500000, NGRP = 10000 };  // fixed by problem spec

// ---------------------------------------------------------------- repack ---
__global__ __launch_bounds__(256) void repack_kernel(
    const float* __restrict__ points_3d,
    const float* __restrict__ ref_poses,
    f4* __restrict__ ws_pts,
    f4* __restrict__ ws_ref)
{
    int i = blockIdx.x * blockDim.x + threadIdx.x;
    if (i < NPTS) {
        const float* p = points_3d + 3 * i;
        f4 v; v.x = p[0]; v.y = p[1]; v.z = p[2]; v.w = 0.0f;
        ws_pts[i] = v;
    } else if (i < NPTS + NGRP) {
        int j = i - NPTS;
        const float* r = ref_poses + 7 * j;
        f4 a; a.x = r[0]; a.y = r[1]; a.z = r[2]; a.w = r[3];
        f4 b; b.x = r[4]; b.y = r[5]; b.z = r[6]; b.w = 0.0f;
        ws_ref[2 * j]     = a;
        ws_ref[2 * j + 1] = b;
    }
}

// ------------------------------------------------------------- projection ---
// ra = (ref_t.xyz, ref_q.x), rb = (ref_q.y, ref_q.z, ref_q.w, _)
__device__ __forceinline__ f2 project_one(
    f4 ra, f4 rb, int m, int cam, f4 P, f2 p2d,
    const float* s_rel, const float* s_pps, const float* s_intr)
{
    float rtx = ra.x, rty = ra.y, rtz = ra.z;
    float rqx = ra.w, rqy = rb.x, rqz = rb.y, rqw = rb.z;

    // rel pose from LDS (7*m strides hit distinct banks: gcd(7,32)=1)
    const float* lp = s_rel + 7 * m;
    float ltx = lp[0], lty = lp[1], ltz = lp[2];
    float lqx = lp[3], lqy = lp[4], lqz = lp[5], lqw = lp[6];

    // t = rel_t + quat_rotate(rel_q, ref_t)
    float uvx = lqy * rtz - lqz * rty;
    float uvy = lqz * rtx - lqx * rtz;
    float uvz = lqx * rty - lqy * rtx;
    float uuvx = lqy * uvz - lqz * uvy;
    float uuvy = lqz * uvx - lqx * uvz;
    float uuvz = lqx * uvy - lqy * uvx;
    float tx = ltx + rtx + 2.0f * (lqw * uvx + uuvx);
    float ty = lty + rty + 2.0f * (lqw * uvy + uuvy);
    float tz = ltz + rtz + 2.0f * (lqw * uvz + uuvz);

    // q = quat_mul(rel_q, ref_q)
    float qw = lqw * rqw - (lqx * rqx + lqy * rqy + lqz * rqz);
    float qx = lqw * rqx + rqw * lqx + (lqy * rqz - lqz * rqy);
    float qy = lqw * rqy + rqw * lqy + (lqz * rqx - lqx * rqz);
    float qz = lqw * rqz + rqw * lqz + (lqx * rqy - lqy * rqx);

    // p_cam = quat_rotate(q, p) + t
    float px = P.x, py = P.y, pz = P.z;
    float v2x = qy * pz - qz * py;
    float v2y = qz * px - qx * pz;
    float v2z = qx * py - qy * px;
    float w2x = qy * v2z - qz * v2y;
    float w2y = qz * v2x - qx * v2z;
    float w2z = qx * v2y - qy * v2x;
    float pcx = px + 2.0f * (qw * v2x + w2x) + tx;
    float pcy = py + 2.0f * (qw * v2y + w2y) + ty;
    float pcz = pz + 2.0f * (qw * v2z + w2z) + tz;

    float invz = 1.0f / pcz;  // IEEE divide for numpy-matching accuracy
    f2 r;
    r.x = s_intr[2 * cam]     * (pcx * invz) + s_pps[2 * cam]     - p2d.x;
    r.y = s_intr[2 * cam + 1] * (pcy * invz) + s_pps[2 * cam + 1] - p2d.y;
    return r;
}

// ------------------------------------------------------------ main kernel ---
template<bool REPACK>
__global__ __launch_bounds__(256) void reproj2_kernel(
    const float2* __restrict__ points_2d,
    const int*    __restrict__ camera_indices,
    const int2*   __restrict__ grouping_indices,
    const int*    __restrict__ point_indices,
    const float*  __restrict__ camera_pps,
    const float*  __restrict__ intrs,
    const float*  __restrict__ points_3d,
    const float*  __restrict__ ref_poses,
    const float*  __restrict__ rel_poses,
    const f4*     __restrict__ ws_pts,
    const f4*     __restrict__ ws_ref,
    float2*       __restrict__ out,
    int n)
{
    __shared__ float s_rel[56];   // 8 rel poses x 7
    __shared__ float s_pps[16];   // 8 cams x 2
    __shared__ float s_intr[16];  // 8 cams x 2
    int tid = threadIdx.x;
    if (tid < 56) s_rel[tid] = rel_poses[tid];
    if (tid < 16) { s_pps[tid] = camera_pps[tid]; s_intr[tid] = intrs[tid]; }
    __syncthreads();

    int t = blockIdx.x * blockDim.x + tid;
    int i = 2 * t;
    if (i >= n) return;

    if (i + 1 < n) {
        // ---- pair path: vectorized streaming loads (nontemporal) ----
        f4 p2 = __builtin_nontemporal_load((const f4*)points_2d + t);
        i4 gm = __builtin_nontemporal_load((const i4*)grouping_indices + t);
        i2 pi = __builtin_nontemporal_load((const i2*)point_indices + t);
        i2 cm = __builtin_nontemporal_load((const i2*)camera_indices + t);

        // ---- issue all gathers before any compute (MLP) ----
        f4 ra0, rb0, ra1, rb1, P0, P1;
        if (REPACK) {
            ra0 = ws_ref[2 * gm.x];  rb0 = ws_ref[2 * gm.x + 1];
            ra1 = ws_ref[2 * gm.z];  rb1 = ws_ref[2 * gm.z + 1];
            P0  = ws_pts[pi.x];      P1  = ws_pts[pi.y];
        } else {
            const float* rp0 = ref_poses + 7 * gm.x;
            const float* rp1 = ref_poses + 7 * gm.z;
            const float* pp0 = points_3d + 3 * pi.x;
            const float* pp1 = points_3d + 3 * pi.y;
            ra0.x = rp0[0]; ra0.y = rp0[1]; ra0.z = rp0[2]; ra0.w = rp0[3];
            rb0.x = rp0[4]; rb0.y = rp0[5]; rb0.z = rp0[6]; rb0.w = 0.0f;
            ra1.x = rp1[0]; ra1.y = rp1[1]; ra1.z = rp1[2]; ra1.w = rp1[3];
            rb1.x = rp1[4]; rb1.y = rp1[5]; rb1.z = rp1[6]; rb1.w = 0.0f;
            P0.x = pp0[0]; P0.y = pp0[1]; P0.z = pp0[2]; P0.w = 0.0f;
            P1.x = pp1[0]; P1.y = pp1[1]; P1.z = pp1[2]; P1.w = 0.0f;
        }

        f2 d0, d1;
        d0.x = p2.x; d0.y = p2.y;
        d1.x = p2.z; d1.y = p2.w;
        f2 r0 = project_one(ra0, rb0, gm.y, cm.x, P0, d0, s_rel, s_pps, s_intr);
        f2 r1 = project_one(ra1, rb1, gm.w, cm.y, P1, d1, s_rel, s_pps, s_intr);

        f4 o; o.x = r0.x; o.y = r0.y; o.z = r1.x; o.w = r1.y;
        __builtin_nontemporal_store(o, (f4*)out + t);
    } else {
        // ---- tail: single element (n odd) ----
        float2 p2d = points_2d[i];
        int2   gm  = grouping_indices[i];
        int    pi  = point_indices[i];
        int    cam = camera_indices[i];

        f4 ra, rb, P;
        if (REPACK) {
            ra = ws_ref[2 * gm.x]; rb = ws_ref[2 * gm.x + 1];
            P  = ws_pts[pi];
        } else {
            const float* rp = ref_poses + 7 * gm.x;
            const float* pp = points_3d + 3 * pi;
            ra.x = rp[0]; ra.y = rp[1]; ra.z = rp[2]; ra.w = rp[3];
            rb.x = rp[4]; rb.y = rp[5]; rb.z = rp[6]; rb.w = 0.0f;
            P.x = pp[0]; P.y = pp[1]; P.z = pp[2]; P.w = 0.0f;
        }
        f2 d; d.x = p2d.x; d.y = p2d.y;
        f2 r = project_one(ra, rb, gm.y, cam, P, d, s_rel, s_pps, s_intr);
        out[i] = make_float2(r.x, r.y);
    }
}

// --------------------------------------------------------------- launcher ---
extern "C" void kernel_launch(void* const* d_in, const int* in_sizes, int n_in,
                              void* d_out, int out_size, void* d_ws, size_t ws_size,
                              hipStream_t stream) {
    const float2* points_2d       = (const float2*)d_in[0];
    const int*    camera_indices  = (const int*)d_in[1];
    const int2*   grouping        = (const int2*)d_in[2];
    const int*    point_indices   = (const int*)d_in[3];
    const float*  camera_pps      = (const float*)d_in[4];
    const float*  intrs           = (const float*)d_in[5];
    const float*  points_3d       = (const float*)d_in[6];
    const float*  ref_poses       = (const float*)d_in[7];
    const float*  rel_poses       = (const float*)d_in[8];
    float2*       out             = (float2*)d_out;

    int n = in_sizes[1];  // N observations (camera_indices is (N,))
    int pair_threads = (n + 1) / 2;
    int blocks = (pair_threads + 255) / 256;

    size_t need = (size_t)NPTS * 16 + (size_t)NGRP * 32;  // 8.32 MB
    if (d_ws && ws_size >= need) {
        f4* ws_pts = (f4*)d_ws;
        f4* ws_ref = (f4*)((char*)d_ws + (size_t)NPTS * 16);
        int rthreads = NPTS + NGRP;
        repack_kernel<<<(rthreads + 255) / 256, 256, 0, stream>>>(
            points_3d, ref_poses, ws_pts, ws_ref);
        reproj2_kernel<true><<<blocks, 256, 0, stream>>>(
            points_2d, camera_indices, grouping, point_indices,
            camera_pps, intrs, points_3d, ref_poses, rel_poses,
            ws_pts, ws_ref, out, n);
    } else {
        reproj2_kernel<false><<<blocks, 256, 0, stream>>>(
            points_2d, camera_indices, grouping, point_indices,
            camera_pps, intrs, points_3d, ref_poses, rel_poses,
            nullptr, nullptr, out, n);
    }
}